// Round 2
// baseline (1069.636 us; speedup 1.0000x reference)
//
#include <hip/hip_runtime.h>
#include <hip/hip_bf16.h>
#include <stdint.h>

using u16 = unsigned short;
using u32 = unsigned int;

typedef __attribute__((ext_vector_type(8))) short short8;
typedef __attribute__((ext_vector_type(4))) float floatx4;

__device__ __forceinline__ u16 f2bf(float f) {
  __hip_bfloat16 h = __float2bfloat16(f);
  return *reinterpret_cast<u16*>(&h);
}

__device__ __forceinline__ void gl_lds16(const void* g, void* l) {
  __builtin_amdgcn_global_load_lds((const __attribute__((address_space(1))) void*)g,
                                   (__attribute__((address_space(3))) void*)l, 16, 0, 0);
}

// ---------------- transpose fp32 [R][Cc] -> bf16 [Cc][R] ----------------
__global__ __launch_bounds__(256)
void transpose_to_bf16(const float* __restrict__ in, u16* __restrict__ out,
                       int R, int Cc) {
  __shared__ float tile[32][33];
  int c0 = blockIdx.x * 32;
  int r0 = blockIdx.y * 32;
  int tx = threadIdx.x;   // 0..31
  int ty = threadIdx.y;   // 0..7
#pragma unroll
  for (int i = 0; i < 32; i += 8)
    tile[ty + i][tx] = in[(size_t)(r0 + ty + i) * Cc + c0 + tx];
  __syncthreads();
#pragma unroll
  for (int i = 0; i < 32; i += 8)
    out[(size_t)(c0 + ty + i) * R + r0 + tx] = f2bf(tile[tx][ty + i]);
}

#define MM(i, j, va, vb) \
  acc[i][j] = __builtin_amdgcn_mfma_f32_16x16x32_bf16(va, vb, acc[i][j], 0, 0, 0)
#define MEMF() asm volatile("" ::: "memory")
#define BAR() do { MEMF(); __builtin_amdgcn_s_barrier(); MEMF(); } while (0)

// ======================================================================
// gemm256: BM=256 x BN=128, BK=64, 512 threads (8 waves = 4M x 2N),
// triple-buffered LDS (144 KiB), counted-vmcnt phase schedule, setprio,
// XOR chunk swizzle, XCD-aware block swizzle. bf16 A. Grid dim3(8, M/256).
// ======================================================================
constexpr int A_BUF  = 256 * 64;      // u16 per A buffer (32 KiB)
constexpr int B_BUF  = 128 * 64;      // u16 per B buffer (16 KiB)
constexpr int B_BASE = 3 * A_BUF;
constexpr int LDS_BYTES = (3 * A_BUF + 3 * B_BUF) * 2;  // 147456

#define STAGE_AH(h, bufo) \
  do { gl_lds16(apt[h][0], lds + (bufo) + adst[h][0]); apt[h][0] += 64; \
       gl_lds16(apt[h][1], lds + (bufo) + adst[h][1]); apt[h][1] += 64; } while (0)
#define STAGE_BH(h, bufo) \
  do { gl_lds16(bpt[h], lds + (bufo) + bdst[h]); bpt[h] += 64; } while (0)

template <bool RELU>
__global__ __launch_bounds__(512, 2)
void gemm256(const u16* __restrict__ A, const u16* __restrict__ BT,
             const float* __restrict__ bias, u16* __restrict__ C,
             int N, int K) {
  extern __shared__ u16 lds[];
  const int tid  = threadIdx.x;
  const int lane = tid & 63;
  const int wave = tid >> 6;
  const int wm = wave >> 1;
  const int wn = wave & 1;
  const int row = lane & 15;
  const int kq  = lane >> 4;
  const int sw  = lane & 7;

  const int orig = blockIdx.y * 8 + blockIdx.x;
  const int rr = ((orig & 7) << 5) | (orig >> 3);
  const int n0 = (rr & 7) * 128;
  const int m0 = (rr >> 3) * 256;

  const int o0 = ((kq) ^ sw) * 8;
  const int o1 = ((4 | kq) ^ sw) * 8;
  const int ar0 = (wm * 64 + row) * 64;
  const int ar1 = ar0 + 16 * 64;
  const int ar2 = ar0 + 32 * 64;
  const int ar3 = ar0 + 48 * 64;
  const int br0 = (wn * 64 + row) * 64;
  const int br1 = br0 + 16 * 64;
  const int br2 = br0 + 32 * 64;
  const int br3 = br0 + 48 * 64;

  const u16* apt[2][2];
  int adst[2][2];
#pragma unroll
  for (int h = 0; h < 2; ++h)
#pragma unroll
    for (int L = 0; L < 2; ++L) {
      int i = L * 512 + tid;
      int rg = h * 128 + (i >> 3);
      int c = i & 7;
      apt[h][L] = A + (size_t)(m0 + rg) * K + ((c ^ (rg & 7)) * 8);
      adst[h][L] = h * 8192 + L * 4096 + wave * 512;
    }
  const u16* bpt[2];
  int bdst[2];
#pragma unroll
  for (int h = 0; h < 2; ++h) {
    int rg = h * 64 + (tid >> 3);
    int c = tid & 7;
    bpt[h] = BT + (size_t)(n0 + rg) * K + ((c ^ (rg & 7)) * 8);
    bdst[h] = B_BASE + h * 4096 + wave * 512;
  }

  STAGE_AH(0, 0);      STAGE_AH(1, 0);      STAGE_BH(0, 0);     STAGE_BH(1, 0);
  STAGE_AH(0, A_BUF);  STAGE_AH(1, A_BUF);  STAGE_BH(0, B_BUF); STAGE_BH(1, B_BUF);
  asm volatile("s_waitcnt vmcnt(6)" ::: "memory");
  BAR();

  floatx4 acc[4][4] = {};
  int cb = 0, sb = 2;
  const int NT = K >> 6;
  for (int T = 0; T < NT; ++T) {
    const bool st = (T + 2 < NT);
    const u16* Ac = lds + cb * A_BUF;
    const u16* Bc = lds + B_BASE + cb * B_BUF;
    const int sA = sb * A_BUF;
    const int sB = sb * B_BUF;

    short8 a0k0, a0k1, a1k0, a1k1, a2k0, a2k1, a3k0, a3k1;
    short8 b0k0, b0k1, b1k0, b1k1, b2k0, b2k1, b3k0, b3k1;

    a0k0 = *(const short8*)(Ac + ar0 + o0);
    a0k1 = *(const short8*)(Ac + ar0 + o1);
    a1k0 = *(const short8*)(Ac + ar1 + o0);
    a1k1 = *(const short8*)(Ac + ar1 + o1);
    b0k0 = *(const short8*)(Bc + br0 + o0);
    b0k1 = *(const short8*)(Bc + br0 + o1);
    b1k0 = *(const short8*)(Bc + br1 + o0);
    b1k1 = *(const short8*)(Bc + br1 + o1);
    if (st) STAGE_AH(0, sA);
    BAR();
    __builtin_amdgcn_s_setprio(1);
    MM(0, 0, a0k0, b0k0); MM(0, 1, a0k0, b1k0);
    MM(1, 0, a1k0, b0k0); MM(1, 1, a1k0, b1k0);
    MM(0, 0, a0k1, b0k1); MM(0, 1, a0k1, b1k1);
    MM(1, 0, a1k1, b0k1); MM(1, 1, a1k1, b1k1);
    __builtin_amdgcn_s_setprio(0);
    BAR();

    b2k0 = *(const short8*)(Bc + br2 + o0);
    b2k1 = *(const short8*)(Bc + br2 + o1);
    b3k0 = *(const short8*)(Bc + br3 + o0);
    b3k1 = *(const short8*)(Bc + br3 + o1);
    if (st) STAGE_AH(1, sA);
    BAR();
    __builtin_amdgcn_s_setprio(1);
    MM(0, 2, a0k0, b2k0); MM(0, 3, a0k0, b3k0);
    MM(1, 2, a1k0, b2k0); MM(1, 3, a1k0, b3k0);
    MM(0, 2, a0k1, b2k1); MM(0, 3, a0k1, b3k1);
    MM(1, 2, a1k1, b2k1); MM(1, 3, a1k1, b3k1);
    __builtin_amdgcn_s_setprio(0);
    BAR();

    a2k0 = *(const short8*)(Ac + ar2 + o0);
    a2k1 = *(const short8*)(Ac + ar2 + o1);
    a3k0 = *(const short8*)(Ac + ar3 + o0);
    a3k1 = *(const short8*)(Ac + ar3 + o1);
    if (st) STAGE_BH(0, sB);
    BAR();
    __builtin_amdgcn_s_setprio(1);
    MM(2, 2, a2k0, b2k0); MM(2, 3, a2k0, b3k0);
    MM(3, 2, a3k0, b2k0); MM(3, 3, a3k0, b3k0);
    MM(2, 2, a2k1, b2k1); MM(2, 3, a2k1, b3k1);
    MM(3, 2, a3k1, b2k1); MM(3, 3, a3k1, b3k1);
    __builtin_amdgcn_s_setprio(0);
    BAR();

    if (st) STAGE_BH(1, sB);
    BAR();
    __builtin_amdgcn_s_setprio(1);
    MM(2, 0, a2k0, b0k0); MM(2, 1, a2k0, b1k0);
    MM(3, 0, a3k0, b0k0); MM(3, 1, a3k0, b1k0);
    MM(2, 0, a2k1, b0k1); MM(2, 1, a2k1, b1k1);
    MM(3, 0, a3k1, b0k1); MM(3, 1, a3k1, b1k1);
    __builtin_amdgcn_s_setprio(0);
    if (st) asm volatile("s_waitcnt vmcnt(6)" ::: "memory");
    else    asm volatile("s_waitcnt vmcnt(0)" ::: "memory");
    BAR();

    cb = (cb == 2) ? 0 : cb + 1;
    sb = (sb == 2) ? 0 : sb + 1;
  }

#pragma unroll
  for (int mt = 0; mt < 4; ++mt) {
#pragma unroll
    for (int nt = 0; nt < 4; ++nt) {
      int gm = m0 + wm * 64 + mt * 16 + kq * 4;
      int gn = n0 + wn * 64 + nt * 16 + row;
      float bv = bias[gn];
#pragma unroll
      for (int r = 0; r < 4; ++r) {
        float v = acc[mt][nt][r] + bv;
        if (RELU) v = fmaxf(v, 0.f);
        C[(size_t)(gm + r) * N + gn] = f2bf(v);
      }
    }
  }
}

// ======================================================================
// gemm256F: fp32 A fused-convert variant (T14 reg-staging for A):
// A loads issued in P0 (3 phases of MFMA cover), cvt+ds_write in P3.
// B via global_load_lds (pre-swizzled source). Double-buffered LDS 96 KiB.
// Eliminates the separate X fp32->bf16 pass entirely.
// ======================================================================
constexpr int FA_BUF  = 256 * 64;     // u16
constexpr int FB_BUF  = 128 * 64;     // u16
constexpr int FB_BASE = 2 * FA_BUF;
constexpr int LDS_BYTES_F = (2 * FA_BUF + 2 * FB_BUF) * 2;  // 98304

__device__ __forceinline__ void cvtw64(u16* dst, float4 v) {
  u32 lo = (u32)f2bf(v.x) | ((u32)f2bf(v.y) << 16);
  u32 hi = (u32)f2bf(v.z) | ((u32)f2bf(v.w) << 16);
  *(uint2*)dst = make_uint2(lo, hi);
}

__global__ __launch_bounds__(512, 2)
void gemm256F(const float* __restrict__ A, const u16* __restrict__ BT,
              const float* __restrict__ bias, u16* __restrict__ C,
              int N, int K) {
  extern __shared__ u16 lds[];
  const int tid  = threadIdx.x;
  const int lane = tid & 63;
  const int wave = tid >> 6;
  const int wm = wave >> 1;
  const int wn = wave & 1;
  const int row = lane & 15;
  const int kq  = lane >> 4;
  const int sw  = lane & 7;

  const int orig = blockIdx.y * 8 + blockIdx.x;
  const int rr = ((orig & 7) << 5) | (orig >> 3);
  const int n0 = (rr & 7) * 128;
  const int m0 = (rr >> 3) * 256;

  const int o0 = ((kq) ^ sw) * 8;
  const int o1 = ((4 | kq) ^ sw) * 8;
  const int ar0 = (wm * 64 + row) * 64;
  const int ar1 = ar0 + 16 * 64;
  const int ar2 = ar0 + 32 * 64;
  const int ar3 = ar0 + 48 * 64;
  const int br0 = (wn * 64 + row) * 64;
  const int br1 = br0 + 16 * 64;
  const int br2 = br0 + 32 * 64;
  const int br3 = br0 + 48 * 64;

  // B staging (global_load_lds, pre-swizzled source, linear dest)
  const u16* bpt[2];
  int bdst[2];
#pragma unroll
  for (int h = 0; h < 2; ++h) {
    int rg = h * 64 + (tid >> 3);
    int c = tid & 7;
    bpt[h] = BT + (size_t)(n0 + rg) * K + ((c ^ (rg & 7)) * 8);
    bdst[h] = h * 4096 + wave * 512;  // relative to B buffer base
  }

  // A reg-staging: load idx = i*512+tid covers row (i*32 + tid>>4), float4 col tid&15
  // fully coalesced 16B x 64 lanes per instruction.
  const float* aFk = A + (size_t)(m0 + (tid >> 4)) * K + (tid & 15) * 4;
  // LDS dest: slot (row, c^(row&7)); row&7 == (tid>>4)&7 for all (h,i).
  const int r0t = tid >> 4;
  const int c4 = tid & 15;
  const int adst0 = r0t * 64 + (((c4 >> 1) ^ (r0t & 7)) * 8) + (c4 & 1) * 4;

  float4 rA[2][4];

#define FSTAGE_ISSUE(nB_)                                              \
  do {                                                                 \
    MEMF();                                                            \
    gl_lds16(bpt[0], lds + (nB_) + bdst[0]); bpt[0] += 64;             \
    gl_lds16(bpt[1], lds + (nB_) + bdst[1]); bpt[1] += 64;             \
    MEMF();                                                            \
    _Pragma("unroll")                                                  \
    for (int h = 0; h < 2; ++h)                                        \
      _Pragma("unroll")                                                \
      for (int i = 0; i < 4; ++i)                                      \
        rA[h][i] = *(const float4*)(aFk + (size_t)(h * 128 + i * 32) * K); \
    aFk += 64;                                                         \
    MEMF();                                                            \
  } while (0)

#define FSTAGE_WRITE(nA_)                                              \
  do {                                                                 \
    asm volatile("s_waitcnt vmcnt(4)" ::: "memory");                   \
    _Pragma("unroll")                                                  \
    for (int i = 0; i < 4; ++i)                                        \
      cvtw64(lds + (nA_) + adst0 + (i * 32) * 64, rA[0][i]);           \
    asm volatile("s_waitcnt vmcnt(0)" ::: "memory");                   \
    _Pragma("unroll")                                                  \
    for (int i = 0; i < 4; ++i)                                        \
      cvtw64(lds + (nA_) + adst0 + ((128 + i * 32)) * 64, rA[1][i]);   \
  } while (0)

  // prologue: tile 0 -> buffer 0
  FSTAGE_ISSUE(FB_BASE + 0);
  FSTAGE_WRITE(0);
  asm volatile("s_waitcnt lgkmcnt(0)" ::: "memory");
  BAR();

  floatx4 acc[4][4] = {};
  const int NT = K >> 6;
  for (int T = 0; T < NT; ++T) {
    const int cur = T & 1;
    const bool st = (T + 1 < NT);
    const u16* Ac = lds + cur * FA_BUF;
    const u16* Bc = lds + FB_BASE + cur * FB_BUF;
    const int nA = (cur ^ 1) * FA_BUF;
    const int nB = FB_BASE + (cur ^ 1) * FB_BUF;

    short8 a0k0, a0k1, a1k0, a1k1, a2k0, a2k1, a3k0, a3k1;
    short8 b0k0, b0k1, b1k0, b1k1, b2k0, b2k1, b3k0, b3k1;

    // ---- P0: ds_read a0,a1,b0,b1 | issue ALL staging for T+1 | 8 MFMA ----
    a0k0 = *(const short8*)(Ac + ar0 + o0);
    a0k1 = *(const short8*)(Ac + ar0 + o1);
    a1k0 = *(const short8*)(Ac + ar1 + o0);
    a1k1 = *(const short8*)(Ac + ar1 + o1);
    b0k0 = *(const short8*)(Bc + br0 + o0);
    b0k1 = *(const short8*)(Bc + br0 + o1);
    b1k0 = *(const short8*)(Bc + br1 + o0);
    b1k1 = *(const short8*)(Bc + br1 + o1);
    if (st) FSTAGE_ISSUE(nB);
    BAR();
    __builtin_amdgcn_s_setprio(1);
    MM(0, 0, a0k0, b0k0); MM(0, 1, a0k0, b1k0);
    MM(1, 0, a1k0, b0k0); MM(1, 1, a1k0, b1k0);
    MM(0, 0, a0k1, b0k1); MM(0, 1, a0k1, b1k1);
    MM(1, 0, a1k1, b0k1); MM(1, 1, a1k1, b1k1);
    __builtin_amdgcn_s_setprio(0);
    BAR();

    // ---- P1 ----
    b2k0 = *(const short8*)(Bc + br2 + o0);
    b2k1 = *(const short8*)(Bc + br2 + o1);
    b3k0 = *(const short8*)(Bc + br3 + o0);
    b3k1 = *(const short8*)(Bc + br3 + o1);
    BAR();
    __builtin_amdgcn_s_setprio(1);
    MM(0, 2, a0k0, b2k0); MM(0, 3, a0k0, b3k0);
    MM(1, 2, a1k0, b2k0); MM(1, 3, a1k0, b3k0);
    MM(0, 2, a0k1, b2k1); MM(0, 3, a0k1, b3k1);
    MM(1, 2, a1k1, b2k1); MM(1, 3, a1k1, b3k1);
    __builtin_amdgcn_s_setprio(0);
    BAR();

    // ---- P2 ----
    a2k0 = *(const short8*)(Ac + ar2 + o0);
    a2k1 = *(const short8*)(Ac + ar2 + o1);
    a3k0 = *(const short8*)(Ac + ar3 + o0);
    a3k1 = *(const short8*)(Ac + ar3 + o1);
    BAR();
    __builtin_amdgcn_s_setprio(1);
    MM(2, 2, a2k0, b2k0); MM(2, 3, a2k0, b3k0);
    MM(3, 2, a3k0, b2k0); MM(3, 3, a3k0, b3k0);
    MM(2, 2, a2k1, b2k1); MM(2, 3, a2k1, b3k1);
    MM(3, 2, a3k1, b2k1); MM(3, 3, a3k1, b3k1);
    __builtin_amdgcn_s_setprio(0);
    BAR();

    // ---- P3: cvt+ds_write A(T+1) | 8 MFMA | publish ----
    if (st) FSTAGE_WRITE(nA);
    __builtin_amdgcn_s_setprio(1);
    MM(2, 0, a2k0, b0k0); MM(2, 1, a2k0, b1k0);
    MM(3, 0, a3k0, b0k0); MM(3, 1, a3k0, b1k0);
    MM(2, 0, a2k1, b0k1); MM(2, 1, a2k1, b1k1);
    MM(3, 0, a3k1, b0k1); MM(3, 1, a3k1, b1k1);
    __builtin_amdgcn_s_setprio(0);
    asm volatile("s_waitcnt lgkmcnt(0)" ::: "memory");
    BAR();
  }

  // epilogue (no ReLU for layer 1)
#pragma unroll
  for (int mt = 0; mt < 4; ++mt) {
#pragma unroll
    for (int nt = 0; nt < 4; ++nt) {
      int gm = m0 + wm * 64 + mt * 16 + kq * 4;
      int gn = n0 + wn * 64 + nt * 16 + row;
      float bv = bias[gn];
#pragma unroll
      for (int r = 0; r < 4; ++r) {
        float v = acc[mt][nt][r] + bv;
        C[(size_t)(gm + r) * N + gn] = f2bf(v);
      }
    }
  }
#undef FSTAGE_ISSUE
#undef FSTAGE_WRITE
}

// ---------------- heads: one wave per row, 4 rows per block ----------------
__device__ __forceinline__ float wave_sum(float v) {
#pragma unroll
  for (int m = 32; m >= 1; m >>= 1) v += __shfl_xor(v, m, 64);
  return v;
}

__global__ __launch_bounds__(256)
void head_kernel(const u16* __restrict__ H, const float* __restrict__ Wc,
                 const float* __restrict__ bc, const float* __restrict__ Wr,
                 const float* __restrict__ br, float* __restrict__ out) {
  const int rowi = blockIdx.x * 4 + (threadIdx.x >> 6);
  const int lane = threadIdx.x & 63;
  const u16* h = H + (size_t)rowi * 1024 + lane * 16;
  uint4 p0 = *(const uint4*)h;
  uint4 p1 = *(const uint4*)(h + 8);
  u32 w[8] = {p0.x, p0.y, p0.z, p0.w, p1.x, p1.y, p1.z, p1.w};
  float x[16];
#pragma unroll
  for (int i = 0; i < 8; ++i) {
    union { u32 u; float f; } lo, hi;
    lo.u = w[i] << 16;
    hi.u = w[i] & 0xffff0000u;
    x[2 * i] = lo.f;
    x[2 * i + 1] = hi.f;
  }
  float ac[4] = {};
  float ar[12] = {};
  const int kbase = lane * 16;
#pragma unroll
  for (int j = 0; j < 16; ++j) {
    float xv = x[j];
    const float* wc = Wc + (size_t)(kbase + j) * 4;
#pragma unroll
    for (int c = 0; c < 4; ++c) ac[c] = fmaf(xv, wc[c], ac[c]);
    const float* wr = Wr + (size_t)(kbase + j) * 12;
#pragma unroll
    for (int r = 0; r < 12; ++r) ar[r] = fmaf(xv, wr[r], ar[r]);
  }
#pragma unroll
  for (int c = 0; c < 4; ++c) ac[c] = wave_sum(ac[c]);
#pragma unroll
  for (int r = 0; r < 12; ++r) ar[r] = wave_sum(ar[r]);

  if (lane == 0) {
    float lg[4], mx = -1e30f;
#pragma unroll
    for (int c = 0; c < 4; ++c) { lg[c] = ac[c] + bc[c]; mx = fmaxf(mx, lg[c]); }
    float s = 0.f;
#pragma unroll
    for (int c = 0; c < 4; ++c) { lg[c] = __expf(lg[c] - mx); s += lg[c]; }
    float inv = 1.f / s;
#pragma unroll
    for (int c = 0; c < 4; ++c) out[(size_t)rowi * 4 + c] = lg[c] * inv;
    float* ob = out + 8192 * 4;
#pragma unroll
    for (int r = 0; r < 12; ++r) ob[(size_t)rowi * 12 + r] = ar[r] + br[r];
  }
}

extern "C" void kernel_launch(void* const* d_in, const int* in_sizes, int n_in,
                              void* d_out, int out_size, void* d_ws, size_t ws_size,
                              hipStream_t stream) {
  const float* X  = (const float*)d_in[0];
  const float* W1 = (const float*)d_in[1];
  const float* b1 = (const float*)d_in[2];
  const float* W2 = (const float*)d_in[3];
  const float* b2 = (const float*)d_in[4];
  const float* Wc = (const float*)d_in[5];
  const float* bc = (const float*)d_in[6];
  const float* Wr = (const float*)d_in[7];
  const float* br = (const float*)d_in[8];

  constexpr int NP = 8192, DIN = 12544, HID = 1024;
  char* ws = (char*)d_ws;
  u16* W1T = (u16*)ws;                                        // HID*DIN bf16
  u16* W2T = (u16*)(ws + (size_t)HID * DIN * 2);              // HID*HID
  u16* H1  = (u16*)((char*)W2T + (size_t)HID * HID * 2);      // NP*HID
  u16* Hb  = H1 + (size_t)NP * HID;                           // NP*HID
  (void)ws_size;

  static bool s_attr = false;
  if (!s_attr) {
    hipFuncSetAttribute(reinterpret_cast<const void*>(gemm256F),
                        hipFuncAttributeMaxDynamicSharedMemorySize, LDS_BYTES_F);
    hipFuncSetAttribute(reinterpret_cast<const void*>(gemm256<true>),
                        hipFuncAttributeMaxDynamicSharedMemorySize, LDS_BYTES);
    s_attr = true;
  }

  transpose_to_bf16<<<dim3(HID / 32, DIN / 32), dim3(32, 8), 0, stream>>>(W1, W1T, DIN, HID);
  transpose_to_bf16<<<dim3(HID / 32, HID / 32), dim3(32, 8), 0, stream>>>(W2, W2T, HID, HID);

  gemm256F<<<dim3(8, NP / 256), 512, LDS_BYTES_F, stream>>>(
      X, W1T, b1, H1, HID, DIN);
  gemm256<true><<<dim3(8, NP / 256), 512, LDS_BYTES, stream>>>(
      H1, W2T, b2, Hb, HID, HID);
  head_kernel<<<NP / 4, 256, 0, stream>>>(Hb, Wc, bc, Wr, br, (float*)d_out);
}

// Round 3
// 1025.094 us; speedup vs baseline: 1.0435x; 1.0435x over previous
//
#include <hip/hip_runtime.h>
#include <hip/hip_bf16.h>
#include <stdint.h>

using u16 = unsigned short;
using u32 = unsigned int;

typedef __attribute__((ext_vector_type(8))) short short8;
typedef __attribute__((ext_vector_type(4))) float floatx4;

__device__ __forceinline__ u16 f2bf(float f) {
  __hip_bfloat16 h = __float2bfloat16(f);
  return *reinterpret_cast<u16*>(&h);
}

__device__ __forceinline__ void gl_lds16(const void* g, void* l) {
  __builtin_amdgcn_global_load_lds((const __attribute__((address_space(1))) void*)g,
                                   (__attribute__((address_space(3))) void*)l, 16, 0, 0);
}

// ---------------- transpose fp32 [R][Cc] -> bf16 [Cc][R] ----------------
__global__ __launch_bounds__(256)
void transpose_to_bf16(const float* __restrict__ in, u16* __restrict__ out,
                       int R, int Cc) {
  __shared__ float tile[32][33];
  int c0 = blockIdx.x * 32;
  int r0 = blockIdx.y * 32;
  int tx = threadIdx.x;   // 0..31
  int ty = threadIdx.y;   // 0..7
#pragma unroll
  for (int i = 0; i < 32; i += 8)
    tile[ty + i][tx] = in[(size_t)(r0 + ty + i) * Cc + c0 + tx];
  __syncthreads();
#pragma unroll
  for (int i = 0; i < 32; i += 8)
    out[(size_t)(c0 + ty + i) * R + r0 + tx] = f2bf(tile[tx][ty + i]);
}

#define MM(i, j, va, vb) \
  acc[i][j] = __builtin_amdgcn_mfma_f32_16x16x32_bf16(va, vb, acc[i][j], 0, 0, 0)
#define MEMF() asm volatile("" ::: "memory")
#define BAR() do { MEMF(); __builtin_amdgcn_s_barrier(); MEMF(); } while (0)

// ======================================================================
// Shared geometry: BM=256 x BN=128, BK=64, 512 threads (8 waves = 4M x 2N),
// triple-buffered LDS (144 KiB), counted-vmcnt schedule, setprio,
// XOR chunk swizzle, XCD-aware block swizzle. Grid dim3(8, M/256).
// ======================================================================
constexpr int A_BUF  = 256 * 64;      // u16 per A buffer (32 KiB)
constexpr int B_BUF  = 128 * 64;      // u16 per B buffer (16 KiB)
constexpr int B_BASE = 3 * A_BUF;
constexpr int LDS_BYTES = (3 * A_BUF + 3 * B_BUF) * 2;  // 147456

#define STAGE_AH(h, bufo) \
  do { gl_lds16(apt[h][0], lds + (bufo) + adst[h][0]); apt[h][0] += 64; \
       gl_lds16(apt[h][1], lds + (bufo) + adst[h][1]); apt[h][1] += 64; } while (0)
#define STAGE_BH(h, bufo) \
  do { gl_lds16(bpt[h], lds + (bufo) + bdst[h]); bpt[h] += 64; } while (0)

// ---------------- gemm256: bf16 A via global_load_lds (layer 2) ----------------
template <bool RELU>
__global__ __launch_bounds__(512, 2)
void gemm256(const u16* __restrict__ A, const u16* __restrict__ BT,
             const float* __restrict__ bias, u16* __restrict__ C,
             int N, int K) {
  extern __shared__ u16 lds[];
  const int tid  = threadIdx.x;
  const int lane = tid & 63;
  const int wave = tid >> 6;
  const int wm = wave >> 1;
  const int wn = wave & 1;
  const int row = lane & 15;
  const int kq  = lane >> 4;
  const int sw  = lane & 7;

  const int orig = blockIdx.y * 8 + blockIdx.x;
  const int rr = ((orig & 7) << 5) | (orig >> 3);
  const int n0 = (rr & 7) * 128;
  const int m0 = (rr >> 3) * 256;

  const int o0 = ((kq) ^ sw) * 8;
  const int o1 = ((4 | kq) ^ sw) * 8;
  const int ar0 = (wm * 64 + row) * 64;
  const int ar1 = ar0 + 16 * 64;
  const int ar2 = ar0 + 32 * 64;
  const int ar3 = ar0 + 48 * 64;
  const int br0 = (wn * 64 + row) * 64;
  const int br1 = br0 + 16 * 64;
  const int br2 = br0 + 32 * 64;
  const int br3 = br0 + 48 * 64;

  const u16* apt[2][2];
  int adst[2][2];
#pragma unroll
  for (int h = 0; h < 2; ++h)
#pragma unroll
    for (int L = 0; L < 2; ++L) {
      int i = L * 512 + tid;
      int rg = h * 128 + (i >> 3);
      int c = i & 7;
      apt[h][L] = A + (size_t)(m0 + rg) * K + ((c ^ (rg & 7)) * 8);
      adst[h][L] = h * 8192 + L * 4096 + wave * 512;
    }
  const u16* bpt[2];
  int bdst[2];
#pragma unroll
  for (int h = 0; h < 2; ++h) {
    int rg = h * 64 + (tid >> 3);
    int c = tid & 7;
    bpt[h] = BT + (size_t)(n0 + rg) * K + ((c ^ (rg & 7)) * 8);
    bdst[h] = B_BASE + h * 4096 + wave * 512;
  }

  STAGE_AH(0, 0);      STAGE_AH(1, 0);      STAGE_BH(0, 0);     STAGE_BH(1, 0);
  STAGE_AH(0, A_BUF);  STAGE_AH(1, A_BUF);  STAGE_BH(0, B_BUF); STAGE_BH(1, B_BUF);
  asm volatile("s_waitcnt vmcnt(6)" ::: "memory");
  BAR();

  floatx4 acc[4][4] = {};
  int cb = 0, sb = 2;
  const int NT = K >> 6;
  for (int T = 0; T < NT; ++T) {
    const bool st = (T + 2 < NT);
    const u16* Ac = lds + cb * A_BUF;
    const u16* Bc = lds + B_BASE + cb * B_BUF;
    const int sA = sb * A_BUF;
    const int sB = sb * B_BUF;

    short8 a0k0, a0k1, a1k0, a1k1, a2k0, a2k1, a3k0, a3k1;
    short8 b0k0, b0k1, b1k0, b1k1, b2k0, b2k1, b3k0, b3k1;

    a0k0 = *(const short8*)(Ac + ar0 + o0);
    a0k1 = *(const short8*)(Ac + ar0 + o1);
    a1k0 = *(const short8*)(Ac + ar1 + o0);
    a1k1 = *(const short8*)(Ac + ar1 + o1);
    b0k0 = *(const short8*)(Bc + br0 + o0);
    b0k1 = *(const short8*)(Bc + br0 + o1);
    b1k0 = *(const short8*)(Bc + br1 + o0);
    b1k1 = *(const short8*)(Bc + br1 + o1);
    if (st) STAGE_AH(0, sA);
    BAR();
    __builtin_amdgcn_s_setprio(1);
    MM(0, 0, a0k0, b0k0); MM(0, 1, a0k0, b1k0);
    MM(1, 0, a1k0, b0k0); MM(1, 1, a1k0, b1k0);
    MM(0, 0, a0k1, b0k1); MM(0, 1, a0k1, b1k1);
    MM(1, 0, a1k1, b0k1); MM(1, 1, a1k1, b1k1);
    __builtin_amdgcn_s_setprio(0);
    BAR();

    b2k0 = *(const short8*)(Bc + br2 + o0);
    b2k1 = *(const short8*)(Bc + br2 + o1);
    b3k0 = *(const short8*)(Bc + br3 + o0);
    b3k1 = *(const short8*)(Bc + br3 + o1);
    if (st) STAGE_AH(1, sA);
    BAR();
    __builtin_amdgcn_s_setprio(1);
    MM(0, 2, a0k0, b2k0); MM(0, 3, a0k0, b3k0);
    MM(1, 2, a1k0, b2k0); MM(1, 3, a1k0, b3k0);
    MM(0, 2, a0k1, b2k1); MM(0, 3, a0k1, b3k1);
    MM(1, 2, a1k1, b2k1); MM(1, 3, a1k1, b3k1);
    __builtin_amdgcn_s_setprio(0);
    BAR();

    a2k0 = *(const short8*)(Ac + ar2 + o0);
    a2k1 = *(const short8*)(Ac + ar2 + o1);
    a3k0 = *(const short8*)(Ac + ar3 + o0);
    a3k1 = *(const short8*)(Ac + ar3 + o1);
    if (st) STAGE_BH(0, sB);
    BAR();
    __builtin_amdgcn_s_setprio(1);
    MM(2, 2, a2k0, b2k0); MM(2, 3, a2k0, b3k0);
    MM(3, 2, a3k0, b2k0); MM(3, 3, a3k0, b3k0);
    MM(2, 2, a2k1, b2k1); MM(2, 3, a2k1, b3k1);
    MM(3, 2, a3k1, b2k1); MM(3, 3, a3k1, b3k1);
    __builtin_amdgcn_s_setprio(0);
    BAR();

    if (st) STAGE_BH(1, sB);
    BAR();
    __builtin_amdgcn_s_setprio(1);
    MM(2, 0, a2k0, b0k0); MM(2, 1, a2k0, b1k0);
    MM(3, 0, a3k0, b0k0); MM(3, 1, a3k0, b1k0);
    MM(2, 0, a2k1, b0k1); MM(2, 1, a2k1, b1k1);
    MM(3, 0, a3k1, b0k1); MM(3, 1, a3k1, b1k1);
    __builtin_amdgcn_s_setprio(0);
    if (st) asm volatile("s_waitcnt vmcnt(6)" ::: "memory");
    else    asm volatile("s_waitcnt vmcnt(0)" ::: "memory");
    BAR();

    cb = (cb == 2) ? 0 : cb + 1;
    sb = (sb == 2) ? 0 : sb + 1;
  }

#pragma unroll
  for (int mt = 0; mt < 4; ++mt) {
#pragma unroll
    for (int nt = 0; nt < 4; ++nt) {
      int gm = m0 + wm * 64 + mt * 16 + kq * 4;
      int gn = n0 + wn * 64 + nt * 16 + row;
      float bv = bias[gn];
#pragma unroll
      for (int r = 0; r < 4; ++r) {
        float v = acc[mt][nt][r] + bv;
        if (RELU) v = fmaxf(v, 0.f);
        C[(size_t)(gm + r) * N + gn] = f2bf(v);
      }
    }
  }
}

// ======================================================================
// gemm256F v2: fp32 A fused-convert, SAME triple-buffer skeleton as
// gemm256 with 2-tile lookahead for A reg-staging (counted vmcnt(10),
// never 0 in steady state). Ping-pong register sets rA0/rA1, statically
// indexed via 2-tile manual unroll. Eliminates the separate cvt pass.
// ======================================================================
__device__ __forceinline__ void cvtw64(u16* dst, float4 v) {
  u32 lo = (u32)f2bf(v.x) | ((u32)f2bf(v.y) << 16);
  u32 hi = (u32)f2bf(v.z) | ((u32)f2bf(v.w) << 16);
  *(uint2*)dst = make_uint2(lo, hi);
}

__global__ __launch_bounds__(512, 2)
void gemm256F(const float* __restrict__ A, const u16* __restrict__ BT,
              const float* __restrict__ bias, u16* __restrict__ C,
              int N, int K) {
  extern __shared__ u16 lds[];
  const int tid  = threadIdx.x;
  const int lane = tid & 63;
  const int wave = tid >> 6;
  const int wm = wave >> 1;
  const int wn = wave & 1;
  const int row = lane & 15;
  const int kq  = lane >> 4;
  const int sw  = lane & 7;

  const int orig = blockIdx.y * 8 + blockIdx.x;
  const int rr = ((orig & 7) << 5) | (orig >> 3);
  const int n0 = (rr & 7) * 128;
  const int m0 = (rr >> 3) * 256;

  const int o0 = ((kq) ^ sw) * 8;
  const int o1 = ((4 | kq) ^ sw) * 8;
  const int ar0 = (wm * 64 + row) * 64;
  const int ar1 = ar0 + 16 * 64;
  const int ar2 = ar0 + 32 * 64;
  const int ar3 = ar0 + 48 * 64;
  const int br0 = (wn * 64 + row) * 64;
  const int br1 = br0 + 16 * 64;
  const int br2 = br0 + 32 * 64;
  const int br3 = br0 + 48 * 64;

  // B staging via gl_lds (pre-swizzled source, linear dest)
  const u16* bpt[2];
  int bdst[2];
#pragma unroll
  for (int h = 0; h < 2; ++h) {
    int rg = h * 64 + (tid >> 3);
    int c = tid & 7;
    bpt[h] = BT + (size_t)(n0 + rg) * K + ((c ^ (rg & 7)) * 8);
    bdst[h] = h * 4096 + wave * 512;  // relative to B buffer base
  }

  // A reg-staging: thread covers rows {i*32 + tid>>4}, float4 col tid&15.
  const float* aFk = A + (size_t)(m0 + (tid >> 4)) * K + (tid & 15) * 4;
  const int r0t = tid >> 4;
  const int c4 = tid & 15;
  const int adst0 = r0t * 64 + (((c4 >> 1) ^ (r0t & 7)) * 8) + (c4 & 1) * 4;

  float4 rA0[8], rA1[8];

  // ---- prologue: B0,A0,B1,A1 in flight; cvt A0 -> Abuf0 ----
  MEMF();
  gl_lds16(bpt[0], lds + B_BASE + bdst[0]); bpt[0] += 64;
  gl_lds16(bpt[1], lds + B_BASE + bdst[1]); bpt[1] += 64;
#pragma unroll
  for (int i = 0; i < 8; ++i)
    rA0[i] = *(const float4*)(aFk + (size_t)(i * 32) * K);
  aFk += 64;
  gl_lds16(bpt[0], lds + B_BASE + B_BUF + bdst[0]); bpt[0] += 64;
  gl_lds16(bpt[1], lds + B_BASE + B_BUF + bdst[1]); bpt[1] += 64;
#pragma unroll
  for (int i = 0; i < 8; ++i)
    rA1[i] = *(const float4*)(aFk + (size_t)(i * 32) * K);
  aFk += 64;
  MEMF();
  asm volatile("s_waitcnt vmcnt(10)" ::: "memory");  // B0 + A0 landed
#pragma unroll
  for (int i = 0; i < 8; ++i)
    cvtw64(lds + adst0 + (i * 32) * 64, rA0[i]);
  asm volatile("s_waitcnt lgkmcnt(0)" ::: "memory");
  BAR();

  floatx4 acc[4][4] = {};
  int cb = 0, sb = 2, anb = 1;
  const int NT = K >> 6;   // must be even (K % 128 == 0)

#define FTILE(T_, RSI, RSW)                                                \
  do {                                                                     \
    const bool st2 = (T_) + 2 < NT;                                        \
    const bool st1 = (T_) + 1 < NT;                                        \
    const u16* Ac = lds + cb * A_BUF;                                      \
    const u16* Bc = lds + B_BASE + cb * B_BUF;                             \
    short8 a0k0, a0k1, a1k0, a1k1, a2k0, a2k1, a3k0, a3k1;                 \
    short8 b0k0, b0k1, b1k0, b1k1, b2k0, b2k1, b3k0, b3k1;                 \
    /* P0: reads | issue T+2 staging (B gl_lds + A regs) | 8 MFMA */       \
    a0k0 = *(const short8*)(Ac + ar0 + o0);                                \
    a0k1 = *(const short8*)(Ac + ar0 + o1);                                \
    a1k0 = *(const short8*)(Ac + ar1 + o0);                                \
    a1k1 = *(const short8*)(Ac + ar1 + o1);                                \
    b0k0 = *(const short8*)(Bc + br0 + o0);                                \
    b0k1 = *(const short8*)(Bc + br0 + o1);                                \
    b1k0 = *(const short8*)(Bc + br1 + o0);                                \
    b1k1 = *(const short8*)(Bc + br1 + o1);                                \
    if (st2) {                                                             \
      MEMF();                                                              \
      gl_lds16(bpt[0], lds + B_BASE + sb * B_BUF + bdst[0]); bpt[0] += 64; \
      gl_lds16(bpt[1], lds + B_BASE + sb * B_BUF + bdst[1]); bpt[1] += 64; \
      _Pragma("unroll")                                                    \
      for (int i = 0; i < 8; ++i)                                          \
        RSI[i] = *(const float4*)(aFk + (size_t)(i * 32) * K);             \
      aFk += 64;                                                           \
      MEMF();                                                              \
    }                                                                      \
    BAR();                                                                 \
    __builtin_amdgcn_s_setprio(1);                                         \
    MM(0, 0, a0k0, b0k0); MM(0, 1, a0k0, b1k0);                            \
    MM(1, 0, a1k0, b0k0); MM(1, 1, a1k0, b1k0);                            \
    MM(0, 0, a0k1, b0k1); MM(0, 1, a0k1, b1k1);                            \
    MM(1, 0, a1k1, b0k1); MM(1, 1, a1k1, b1k1);                            \
    __builtin_amdgcn_s_setprio(0);                                         \
    BAR();                                                                 \
    /* P1 */                                                               \
    b2k0 = *(const short8*)(Bc + br2 + o0);                                \
    b2k1 = *(const short8*)(Bc + br2 + o1);                                \
    b3k0 = *(const short8*)(Bc + br3 + o0);                                \
    b3k1 = *(const short8*)(Bc + br3 + o1);                                \
    BAR();                                                                 \
    __builtin_amdgcn_s_setprio(1);                                         \
    MM(0, 2, a0k0, b2k0); MM(0, 3, a0k0, b3k0);                            \
    MM(1, 2, a1k0, b2k0); MM(1, 3, a1k0, b3k0);                            \
    MM(0, 2, a0k1, b2k1); MM(0, 3, a0k1, b3k1);                            \
    MM(1, 2, a1k1, b2k1); MM(1, 3, a1k1, b3k1);                            \
    __builtin_amdgcn_s_setprio(0);                                         \
    BAR();                                                                 \
    /* P2 */                                                               \
    a2k0 = *(const short8*)(Ac + ar2 + o0);                                \
    a2k1 = *(const short8*)(Ac + ar2 + o1);                                \
    a3k0 = *(const short8*)(Ac + ar3 + o0);                                \
    a3k1 = *(const short8*)(Ac + ar3 + o1);                                \
    BAR();                                                                 \
    __builtin_amdgcn_s_setprio(1);                                         \
    MM(2, 2, a2k0, b2k0); MM(2, 3, a2k0, b3k0);                            \
    MM(3, 2, a3k0, b2k0); MM(3, 3, a3k0, b3k0);                            \
    MM(2, 2, a2k1, b2k1); MM(2, 3, a2k1, b3k1);                            \
    MM(3, 2, a3k1, b2k1); MM(3, 3, a3k1, b3k1);                            \
    __builtin_amdgcn_s_setprio(0);                                         \
    BAR();                                                                 \
    /* P3: counted vmcnt | cvt+write T+1's A | 8 MFMA | publish */         \
    if (st1) {                                                             \
      if (st2) asm volatile("s_waitcnt vmcnt(10)" ::: "memory");           \
      else     asm volatile("s_waitcnt vmcnt(0)" ::: "memory");            \
      u16* Aw = lds + anb * A_BUF;                                         \
      _Pragma("unroll")                                                    \
      for (int i = 0; i < 8; ++i)                                          \
        cvtw64(Aw + adst0 + (i * 32) * 64, RSW[i]);                        \
    }                                                                      \
    __builtin_amdgcn_s_setprio(1);                                         \
    MM(2, 0, a2k0, b0k0); MM(2, 1, a2k0, b1k0);                            \
    MM(3, 0, a3k0, b0k0); MM(3, 1, a3k0, b1k0);                            \
    MM(2, 0, a2k1, b0k1); MM(2, 1, a2k1, b1k1);                            \
    MM(3, 0, a3k1, b0k1); MM(3, 1, a3k1, b1k1);                            \
    __builtin_amdgcn_s_setprio(0);                                         \
    asm volatile("s_waitcnt lgkmcnt(0)" ::: "memory");                     \
    BAR();                                                                 \
    cb = (cb == 2) ? 0 : cb + 1;                                           \
    sb = (sb == 2) ? 0 : sb + 1;                                           \
    anb = (anb == 2) ? 0 : anb + 1;                                        \
  } while (0)

  for (int T = 0; T < NT; T += 2) {
    FTILE(T, rA0, rA1);
    FTILE(T + 1, rA1, rA0);
  }
#undef FTILE

  // epilogue (no ReLU for layer 1)
#pragma unroll
  for (int mt = 0; mt < 4; ++mt) {
#pragma unroll
    for (int nt = 0; nt < 4; ++nt) {
      int gm = m0 + wm * 64 + mt * 16 + kq * 4;
      int gn = n0 + wn * 64 + nt * 16 + row;
      float bv = bias[gn];
#pragma unroll
      for (int r = 0; r < 4; ++r) {
        float v = acc[mt][nt][r] + bv;
        C[(size_t)(gm + r) * N + gn] = f2bf(v);
      }
    }
  }
}

// ---------------- heads: one wave per row, 4 rows per block ----------------
__device__ __forceinline__ float wave_sum(float v) {
#pragma unroll
  for (int m = 32; m >= 1; m >>= 1) v += __shfl_xor(v, m, 64);
  return v;
}

__global__ __launch_bounds__(256)
void head_kernel(const u16* __restrict__ H, const float* __restrict__ Wc,
                 const float* __restrict__ bc, const float* __restrict__ Wr,
                 const float* __restrict__ br, float* __restrict__ out) {
  const int rowi = blockIdx.x * 4 + (threadIdx.x >> 6);
  const int lane = threadIdx.x & 63;
  const u16* h = H + (size_t)rowi * 1024 + lane * 16;
  uint4 p0 = *(const uint4*)h;
  uint4 p1 = *(const uint4*)(h + 8);
  u32 w[8] = {p0.x, p0.y, p0.z, p0.w, p1.x, p1.y, p1.z, p1.w};
  float x[16];
#pragma unroll
  for (int i = 0; i < 8; ++i) {
    union { u32 u; float f; } lo, hi;
    lo.u = w[i] << 16;
    hi.u = w[i] & 0xffff0000u;
    x[2 * i] = lo.f;
    x[2 * i + 1] = hi.f;
  }
  float ac[4] = {};
  float ar[12] = {};
  const int kbase = lane * 16;
#pragma unroll
  for (int j = 0; j < 16; ++j) {
    float xv = x[j];
    const float* wc = Wc + (size_t)(kbase + j) * 4;
#pragma unroll
    for (int c = 0; c < 4; ++c) ac[c] = fmaf(xv, wc[c], ac[c]);
    const float* wr = Wr + (size_t)(kbase + j) * 12;
#pragma unroll
    for (int r = 0; r < 12; ++r) ar[r] = fmaf(xv, wr[r], ar[r]);
  }
#pragma unroll
  for (int c = 0; c < 4; ++c) ac[c] = wave_sum(ac[c]);
#pragma unroll
  for (int r = 0; r < 12; ++r) ar[r] = wave_sum(ar[r]);

  if (lane == 0) {
    float lg[4], mx = -1e30f;
#pragma unroll
    for (int c = 0; c < 4; ++c) { lg[c] = ac[c] + bc[c]; mx = fmaxf(mx, lg[c]); }
    float s = 0.f;
#pragma unroll
    for (int c = 0; c < 4; ++c) { lg[c] = __expf(lg[c] - mx); s += lg[c]; }
    float inv = 1.f / s;
#pragma unroll
    for (int c = 0; c < 4; ++c) out[(size_t)rowi * 4 + c] = lg[c] * inv;
    float* ob = out + 8192 * 4;
#pragma unroll
    for (int r = 0; r < 12; ++r) ob[(size_t)rowi * 12 + r] = ar[r] + br[r];
  }
}

extern "C" void kernel_launch(void* const* d_in, const int* in_sizes, int n_in,
                              void* d_out, int out_size, void* d_ws, size_t ws_size,
                              hipStream_t stream) {
  const float* X  = (const float*)d_in[0];
  const float* W1 = (const float*)d_in[1];
  const float* b1 = (const float*)d_in[2];
  const float* W2 = (const float*)d_in[3];
  const float* b2 = (const float*)d_in[4];
  const float* Wc = (const float*)d_in[5];
  const float* bc = (const float*)d_in[6];
  const float* Wr = (const float*)d_in[7];
  const float* br = (const float*)d_in[8];

  constexpr int NP = 8192, DIN = 12544, HID = 1024;
  char* ws = (char*)d_ws;
  u16* W1T = (u16*)ws;                                        // HID*DIN bf16
  u16* W2T = (u16*)(ws + (size_t)HID * DIN * 2);              // HID*HID
  u16* H1  = (u16*)((char*)W2T + (size_t)HID * HID * 2);      // NP*HID
  u16* Hb  = H1 + (size_t)NP * HID;                           // NP*HID
  (void)ws_size;

  static bool s_attr = false;
  if (!s_attr) {
    hipFuncSetAttribute(reinterpret_cast<const void*>(gemm256F),
                        hipFuncAttributeMaxDynamicSharedMemorySize, LDS_BYTES);
    hipFuncSetAttribute(reinterpret_cast<const void*>(gemm256<true>),
                        hipFuncAttributeMaxDynamicSharedMemorySize, LDS_BYTES);
    s_attr = true;
  }

  transpose_to_bf16<<<dim3(HID / 32, DIN / 32), dim3(32, 8), 0, stream>>>(W1, W1T, DIN, HID);
  transpose_to_bf16<<<dim3(HID / 32, HID / 32), dim3(32, 8), 0, stream>>>(W2, W2T, HID, HID);

  gemm256F<<<dim3(8, NP / 256), 512, LDS_BYTES, stream>>>(
      X, W1T, b1, H1, HID, DIN);
  gemm256<true><<<dim3(8, NP / 256), 512, LDS_BYTES, stream>>>(
      H1, W2T, b2, Hb, HID, HID);
  head_kernel<<<NP / 4, 256, 0, stream>>>(Hb, Wc, bc, Wr, br, (float*)d_out);
}